// Round 3
// baseline (306.758 us; speedup 1.0000x reference)
//
#include <hip/hip_runtime.h>
#include <hip/hip_bf16.h>

// Problem constants (fixed by the reference's setup_inputs)
#define C_DIM 64
#define P_DIM 16
#define K_DIM 9            // K1*K1
#define PK (P_DIM * K_DIM) // 144
#define INV2S 0.35355339059327373f  // 1/(2*sqrt(2))

// Counting-sort parameters: bucket = col >> BSHIFT
#define BSHIFT 2
#define NB 16384           // covers col < 65536 (N = 50000)

// ---------------------------------------------------------------------------
// out[n*16+p] = bias[p]
// ---------------------------------------------------------------------------
__global__ __launch_bounds__(256) void init_out_kernel(float* __restrict__ out,
                                                       const float* __restrict__ bias,
                                                       int total) {
    int i = blockIdx.x * 256 + threadIdx.x;
    if (i < total) out[i] = bias[i & (P_DIM - 1)];
}

__global__ __launch_bounds__(256) void zero_hist_kernel(int* __restrict__ hist) {
    int i = blockIdx.x * 256 + threadIdx.x;
    if (i < NB) hist[i] = 0;
}

// ---------------------------------------------------------------------------
// Z[n, p, k] = sum_c x[n,c] * W[p,k,c]   (N x 144 GEMM, K=64)
// ---------------------------------------------------------------------------
__global__ __launch_bounds__(256) void z_gemm_kernel(const float* __restrict__ x,
                                                     const float* __restrict__ W,
                                                     float* __restrict__ Z,
                                                     int N) {
    __shared__ float Ws[C_DIM][PK + 1];
    __shared__ float xs[C_DIM][C_DIM + 1];

    const int block_row = blockIdx.x * 64;

    for (int i = threadIdx.x; i < PK * C_DIM; i += 256) {
        int j = i >> 6, c = i & 63;
        Ws[c][j] = W[i];
    }
    for (int i = threadIdx.x; i < C_DIM * C_DIM; i += 256) {
        int r = i >> 6, c = i & 63;
        int gr = block_row + r;
        xs[c][r] = (gr < N) ? x[(size_t)gr * C_DIM + c] : 0.0f;
    }
    __syncthreads();

    const int rg = threadIdx.x & 15;
    const int p  = threadIdx.x >> 4;

    float acc[4][K_DIM];
    #pragma unroll
    for (int i = 0; i < 4; ++i)
        #pragma unroll
        for (int k = 0; k < K_DIM; ++k) acc[i][k] = 0.0f;

    #pragma unroll 4
    for (int c = 0; c < C_DIM; ++c) {
        float xv[4];
        #pragma unroll
        for (int i = 0; i < 4; ++i) xv[i] = xs[c][rg * 4 + i];
        float wv[K_DIM];
        #pragma unroll
        for (int k = 0; k < K_DIM; ++k) wv[k] = Ws[c][p * K_DIM + k];
        #pragma unroll
        for (int i = 0; i < 4; ++i)
            #pragma unroll
            for (int k = 0; k < K_DIM; ++k)
                acc[i][k] = fmaf(xv[i], wv[k], acc[i][k]);
    }

    #pragma unroll
    for (int i = 0; i < 4; ++i) {
        int gr = block_row + rg * 4 + i;
        if (gr < N) {
            float* zp = Z + (size_t)gr * PK + p * K_DIM;
            #pragma unroll
            for (int k = 0; k < K_DIM; ++k) zp[k] = acc[i][k];
        }
    }
}

// ---------------------------------------------------------------------------
// Counting sort by col: histogram -> exclusive scan -> scatter
// ---------------------------------------------------------------------------
__global__ __launch_bounds__(256) void hist_kernel(const int* __restrict__ ei,
                                                   int* __restrict__ hist, int E) {
    int i = blockIdx.x * 256 + threadIdx.x;
    if (i < E) atomicAdd(&hist[ei[E + i] >> BSHIFT], 1);
}

// single block, 256 threads: in-place exclusive scan of hist[NB]
__global__ __launch_bounds__(256) void scan_kernel(int* __restrict__ hist) {
    __shared__ int sums[256];
    const int per = NB / 256;  // 64
    const int base = threadIdx.x * per;

    int s = 0;
    for (int i = 0; i < per; ++i) s += hist[base + i];
    sums[threadIdx.x] = s;
    __syncthreads();
    // inclusive Hillis-Steele scan over 256 entries
    for (int off = 1; off < 256; off <<= 1) {
        int v = (threadIdx.x >= off) ? sums[threadIdx.x - off] : 0;
        __syncthreads();
        sums[threadIdx.x] += v;
        __syncthreads();
    }
    int run = sums[threadIdx.x] - s;  // exclusive prefix for this thread's chunk
    for (int i = 0; i < per; ++i) {
        int h = hist[base + i];
        hist[base + i] = run;
        run += h;
    }
}

// scatter edges into col-bucket order; precompute d = (pos[c]-pos[r])*INV2S
__global__ __launch_bounds__(256) void scatter_kernel(const int* __restrict__ ei,
                                                      const float* __restrict__ pos,
                                                      int* __restrict__ offs,
                                                      float4* __restrict__ sorted,
                                                      int E) {
    int i = blockIdx.x * 256 + threadIdx.x;
    if (i >= E) return;
    const int r = ei[i];
    const int c = ei[E + i];
    const float d0 = (pos[2 * c]     - pos[2 * r])     * INV2S;
    const float d1 = (pos[2 * c + 1] - pos[2 * r + 1]) * INV2S;
    const int pidx = atomicAdd(&offs[c >> BSHIFT], 1);
    sorted[pidx] = make_float4(d0, d1, __int_as_float(r), __int_as_float(c));
}

// ---------------------------------------------------------------------------
// Edge kernel over col-sorted edges: thread = (e, p); 16 lanes share an edge.
// ---------------------------------------------------------------------------
__global__ __launch_bounds__(256) void edge_sorted_kernel(const float4* __restrict__ sorted,
                                                          const float* __restrict__ pose,
                                                          const float* __restrict__ Z,
                                                          float* __restrict__ out,
                                                          int E) {
    long long tid = (long long)blockIdx.x * 256 + threadIdx.x;
    if (tid >= (long long)E * P_DIM) return;
    const int e = (int)(tid >> 4);
    const int p = (int)(tid & 15);

    const float4 ed = sorted[e];          // broadcast across the 16 lanes
    const float d0 = ed.x, d1 = ed.y;
    const int r = __float_as_int(ed.z);
    const int c = __float_as_int(ed.w);

    const float2 ab = ((const float2*)pose)[(size_t)r * P_DIM + p];
    const float p0 = fmaf(ab.x, d0, fmaf(-ab.y, d1, 0.5f));
    const float p1 = fmaf(ab.y, d0, fmaf( ab.x, d1, 0.5f));

    const float v0 = fminf(fmaxf(p0, 0.0f), 1.0f) * 2.0f;
    const float v1 = fminf(fmaxf(p1, 0.0f), 1.0f) * 2.0f;
    const float lo0 = floorf(v0);
    const float lo1 = floorf(v1);
    const float f0 = v0 - lo0;
    const float f1 = v1 - lo1;
    const int i00 = min((int)lo0, 2);
    const int i01 = min((int)lo0 + 1, 2);
    const int i10 = min((int)lo1, 2);
    const int i11 = min((int)lo1 + 1, 2);

    const float* __restrict__ Zp = Z + (size_t)c * PK + p * K_DIM;
    const float w00 = (1.0f - f0) * (1.0f - f1);
    const float w01 = (1.0f - f0) * f1;
    const float w10 = f0 * (1.0f - f1);
    const float w11 = f0 * f1;

    float m = w00 * Zp[i00 + 3 * i10];
    m = fmaf(w01, Zp[i00 + 3 * i11], m);
    m = fmaf(w10, Zp[i01 + 3 * i10], m);
    m = fmaf(w11, Zp[i01 + 3 * i11], m);

    atomicAdd(&out[(size_t)r * P_DIM + p], m);
}

// Fallback (unsorted) edge kernel, used only if ws_size is too small for sort
__global__ __launch_bounds__(256) void edge_kernel(const int* __restrict__ ei,
                                                   const float* __restrict__ pos,
                                                   const float* __restrict__ pose,
                                                   const float* __restrict__ Z,
                                                   float* __restrict__ out,
                                                   int E) {
    long long tid = (long long)blockIdx.x * 256 + threadIdx.x;
    if (tid >= (long long)E * P_DIM) return;
    const int e = (int)(tid >> 4);
    const int p = (int)(tid & 15);

    const int r = ei[e];
    const int c = ei[E + e];

    const float d0 = (pos[2 * c]     - pos[2 * r])     * INV2S;
    const float d1 = (pos[2 * c + 1] - pos[2 * r + 1]) * INV2S;

    const float2 ab = ((const float2*)pose)[(size_t)r * P_DIM + p];
    const float p0 = fmaf(ab.x, d0, fmaf(-ab.y, d1, 0.5f));
    const float p1 = fmaf(ab.y, d0, fmaf( ab.x, d1, 0.5f));

    const float v0 = fminf(fmaxf(p0, 0.0f), 1.0f) * 2.0f;
    const float v1 = fminf(fmaxf(p1, 0.0f), 1.0f) * 2.0f;
    const float lo0 = floorf(v0);
    const float lo1 = floorf(v1);
    const float f0 = v0 - lo0;
    const float f1 = v1 - lo1;
    const int i00 = min((int)lo0, 2);
    const int i01 = min((int)lo0 + 1, 2);
    const int i10 = min((int)lo1, 2);
    const int i11 = min((int)lo1 + 1, 2);

    const float* __restrict__ Zp = Z + (size_t)c * PK + p * K_DIM;
    const float w00 = (1.0f - f0) * (1.0f - f1);
    const float w01 = (1.0f - f0) * f1;
    const float w10 = f0 * (1.0f - f1);
    const float w11 = f0 * f1;

    float m = w00 * Zp[i00 + 3 * i10];
    m = fmaf(w01, Zp[i00 + 3 * i11], m);
    m = fmaf(w10, Zp[i01 + 3 * i10], m);
    m = fmaf(w11, Zp[i01 + 3 * i11], m);

    atomicAdd(&out[(size_t)r * P_DIM + p], m);
}

// ---------------------------------------------------------------------------
extern "C" void kernel_launch(void* const* d_in, const int* in_sizes, int n_in,
                              void* d_out, int out_size, void* d_ws, size_t ws_size,
                              hipStream_t stream) {
    const float* x    = (const float*)d_in[0];
    const float* pos  = (const float*)d_in[1];
    const float* pose = (const float*)d_in[2];
    const float* W    = (const float*)d_in[3];
    const float* bias = (const float*)d_in[4];
    const int*   ei   = (const int*)d_in[5];

    const int N = in_sizes[0] / C_DIM;   // 50000
    const int E = in_sizes[5] / 2;       // 800000

    float* out = (float*)d_out;

    // workspace layout
    const size_t z_bytes    = (size_t)N * PK * sizeof(float);       // 28,800,000 (16B-aligned)
    const size_t hist_bytes = (size_t)NB * sizeof(int);             // 65,536
    const size_t sort_bytes = (size_t)E * sizeof(float4);           // 12,800,000
    float*  Z      = (float*)d_ws;
    int*    hist   = (int*)((char*)d_ws + z_bytes);
    float4* sorted = (float4*)((char*)d_ws + z_bytes + hist_bytes);
    const bool can_sort = ws_size >= z_bytes + hist_bytes + sort_bytes;

    init_out_kernel<<<(N * P_DIM + 255) / 256, 256, 0, stream>>>(out, bias, N * P_DIM);
    z_gemm_kernel<<<(N + 63) / 64, 256, 0, stream>>>(x, W, Z, N);

    const long long total = (long long)E * P_DIM;
    if (can_sort) {
        zero_hist_kernel<<<NB / 256, 256, 0, stream>>>(hist);
        hist_kernel<<<(E + 255) / 256, 256, 0, stream>>>(ei, hist, E);
        scan_kernel<<<1, 256, 0, stream>>>(hist);
        scatter_kernel<<<(E + 255) / 256, 256, 0, stream>>>(ei, pos, hist, sorted, E);
        edge_sorted_kernel<<<(int)((total + 255) / 256), 256, 0, stream>>>(sorted, pose, Z, out, E);
    } else {
        edge_kernel<<<(int)((total + 255) / 256), 256, 0, stream>>>(ei, pos, pose, Z, out, E);
    }
}

// Round 4
// 283.069 us; speedup vs baseline: 1.0837x; 1.0837x over previous
//
#include <hip/hip_runtime.h>
#include <hip/hip_bf16.h>

// Problem constants (fixed by the reference's setup_inputs)
#define C_DIM 64
#define P_DIM 16
#define K_DIM 9            // K1*K1
#define PK (P_DIM * K_DIM) // 144
#define INV2S 0.35355339059327373f  // 1/(2*sqrt(2))

// Counting-sort parameters: bucket = row >> BSHIFT
#define BSHIFT 2
#define NB 16384           // covers row < 65536 (N = 50000)

// Edge kernel tiling
#define EPB 512            // edges per block
#define TILE_R 256         // LDS out-tile rows (16 KB)

// ---------------------------------------------------------------------------
// out[n*16+p] = bias[p]
// ---------------------------------------------------------------------------
__global__ __launch_bounds__(256) void init_out_kernel(float* __restrict__ out,
                                                       const float* __restrict__ bias,
                                                       int total) {
    int i = blockIdx.x * 256 + threadIdx.x;
    if (i < total) out[i] = bias[i & (P_DIM - 1)];
}

__global__ __launch_bounds__(256) void zero_hist_kernel(int* __restrict__ hist) {
    int i = blockIdx.x * 256 + threadIdx.x;
    if (i < NB) hist[i] = 0;
}

// ---------------------------------------------------------------------------
// Zb[n, p*9+k] (bf16) = sum_c x[n,c] * W[p,k,c]   (N x 144 GEMM, K=64)
// ---------------------------------------------------------------------------
__global__ __launch_bounds__(256) void z_gemm_kernel(const float* __restrict__ x,
                                                     const float* __restrict__ W,
                                                     __hip_bfloat16* __restrict__ Zb,
                                                     int N) {
    __shared__ float Ws[C_DIM][PK + 1];
    __shared__ float xs[C_DIM][C_DIM + 1];

    const int block_row = blockIdx.x * 64;

    for (int i = threadIdx.x; i < PK * C_DIM; i += 256) {
        int j = i >> 6, c = i & 63;
        Ws[c][j] = W[i];
    }
    for (int i = threadIdx.x; i < C_DIM * C_DIM; i += 256) {
        int r = i >> 6, c = i & 63;
        int gr = block_row + r;
        xs[c][r] = (gr < N) ? x[(size_t)gr * C_DIM + c] : 0.0f;
    }
    __syncthreads();

    const int rg = threadIdx.x & 15;
    const int p  = threadIdx.x >> 4;

    float acc[4][K_DIM];
    #pragma unroll
    for (int i = 0; i < 4; ++i)
        #pragma unroll
        for (int k = 0; k < K_DIM; ++k) acc[i][k] = 0.0f;

    #pragma unroll 4
    for (int c = 0; c < C_DIM; ++c) {
        float xv[4];
        #pragma unroll
        for (int i = 0; i < 4; ++i) xv[i] = xs[c][rg * 4 + i];
        float wv[K_DIM];
        #pragma unroll
        for (int k = 0; k < K_DIM; ++k) wv[k] = Ws[c][p * K_DIM + k];
        #pragma unroll
        for (int i = 0; i < 4; ++i)
            #pragma unroll
            for (int k = 0; k < K_DIM; ++k)
                acc[i][k] = fmaf(xv[i], wv[k], acc[i][k]);
    }

    #pragma unroll
    for (int i = 0; i < 4; ++i) {
        int gr = block_row + rg * 4 + i;
        if (gr < N) {
            __hip_bfloat16* zp = Zb + (size_t)gr * PK + p * K_DIM;
            #pragma unroll
            for (int k = 0; k < K_DIM; ++k) zp[k] = __float2bfloat16(acc[i][k]);
        }
    }
}

// ---------------------------------------------------------------------------
// Counting sort by row: histogram -> exclusive scan -> scatter
// ---------------------------------------------------------------------------
__global__ __launch_bounds__(256) void hist_kernel(const int* __restrict__ ei,
                                                   int* __restrict__ hist, int E) {
    int i = blockIdx.x * 256 + threadIdx.x;
    if (i < E) atomicAdd(&hist[ei[i] >> BSHIFT], 1);   // key = row
}

// single block, 256 threads: in-place exclusive scan of hist[NB]
__global__ __launch_bounds__(256) void scan_kernel(int* __restrict__ hist) {
    __shared__ int sums[256];
    const int per = NB / 256;  // 64
    const int base = threadIdx.x * per;

    int s = 0;
    for (int i = 0; i < per; ++i) s += hist[base + i];
    sums[threadIdx.x] = s;
    __syncthreads();
    for (int off = 1; off < 256; off <<= 1) {
        int v = (threadIdx.x >= off) ? sums[threadIdx.x - off] : 0;
        __syncthreads();
        sums[threadIdx.x] += v;
        __syncthreads();
    }
    int run = sums[threadIdx.x] - s;
    for (int i = 0; i < per; ++i) {
        int h = hist[base + i];
        hist[base + i] = run;
        run += h;
    }
}

// scatter edges into row-bucket order; precompute d = (pos[c]-pos[r])*INV2S
__global__ __launch_bounds__(256) void scatter_kernel(const int* __restrict__ ei,
                                                      const float* __restrict__ pos,
                                                      int* __restrict__ offs,
                                                      float4* __restrict__ sorted,
                                                      int E) {
    int i = blockIdx.x * 256 + threadIdx.x;
    if (i >= E) return;
    const int r = ei[i];
    const int c = ei[E + i];
    const float d0 = (pos[2 * c]     - pos[2 * r])     * INV2S;
    const float d1 = (pos[2 * c + 1] - pos[2 * r + 1]) * INV2S;
    const int pidx = atomicAdd(&offs[r >> BSHIFT], 1);
    sorted[pidx] = make_float4(d0, d1, __int_as_float(r), __int_as_float(c));
}

// ---------------------------------------------------------------------------
// Edge kernel over row-sorted edges. Block covers EPB edges; rows fall in a
// narrow contiguous range -> accumulate into LDS tile, flush once.
// thread = (eg = tid>>4, p = tid&15); 16 lanes share an edge.
// ---------------------------------------------------------------------------
__global__ __launch_bounds__(256) void edge_row_kernel(const float4* __restrict__ sorted,
                                                       const float* __restrict__ pose,
                                                       const __hip_bfloat16* __restrict__ Zb,
                                                       float* __restrict__ out,
                                                       int E, int N) {
    __shared__ float tile[TILE_R * P_DIM];
    __shared__ int s_rlo;

    const int e0 = blockIdx.x * EPB;
    const int p  = threadIdx.x & 15;
    const int eg = threadIdx.x >> 4;

    for (int i = threadIdx.x; i < TILE_R * P_DIM; i += 256) tile[i] = 0.0f;
    if (threadIdx.x == 0) {
        int rfirst = __float_as_int(sorted[e0].z);
        s_rlo = (rfirst >> BSHIFT) << BSHIFT;   // bucket floor: rows are >= this
    }
    __syncthreads();
    const int r_lo = s_rlo;

    #pragma unroll 1
    for (int it = 0; it < EPB / 16; ++it) {
        const int e = e0 + it * 16 + eg;
        if (e >= E) break;

        const float4 ed = sorted[e];            // broadcast across 16 lanes
        const float d0 = ed.x, d1 = ed.y;
        const int r = __float_as_int(ed.z);
        const int c = __float_as_int(ed.w);

        const float2 ab = ((const float2*)pose)[(size_t)r * P_DIM + p];
        const float p0 = fmaf(ab.x, d0, fmaf(-ab.y, d1, 0.5f));
        const float p1 = fmaf(ab.y, d0, fmaf( ab.x, d1, 0.5f));

        const float v0 = fminf(fmaxf(p0, 0.0f), 1.0f) * 2.0f;
        const float v1 = fminf(fmaxf(p1, 0.0f), 1.0f) * 2.0f;
        const float lo0 = floorf(v0);
        const float lo1 = floorf(v1);
        const float f0 = v0 - lo0;
        const float f1 = v1 - lo1;
        const int i00 = min((int)lo0, 2);
        const int i01 = min((int)lo0 + 1, 2);
        const int i10 = min((int)lo1, 2);
        const int i11 = min((int)lo1 + 1, 2);

        const __hip_bfloat16* __restrict__ Zp = Zb + (size_t)c * PK + p * K_DIM;
        const float w00 = (1.0f - f0) * (1.0f - f1);
        const float w01 = (1.0f - f0) * f1;
        const float w10 = f0 * (1.0f - f1);
        const float w11 = f0 * f1;

        float m = w00 * __bfloat162float(Zp[i00 + 3 * i10]);
        m = fmaf(w01, __bfloat162float(Zp[i00 + 3 * i11]), m);
        m = fmaf(w10, __bfloat162float(Zp[i01 + 3 * i10]), m);
        m = fmaf(w11, __bfloat162float(Zp[i01 + 3 * i11]), m);

        const int rl = r - r_lo;
        if (rl < TILE_R) atomicAdd(&tile[rl * P_DIM + p], m);   // ds_add_f32
        else             atomicAdd(&out[(size_t)r * P_DIM + p], m);  // rare fallback
    }
    __syncthreads();

    for (int i = threadIdx.x; i < TILE_R * P_DIM; i += 256) {
        float v = tile[i];
        int r = r_lo + (i >> 4);
        if (v != 0.0f && r < N)
            atomicAdd(&out[(size_t)r * P_DIM + (i & 15)], v);
    }
}

// Fallback (unsorted) edge kernel, used only if ws_size is too small for sort
__global__ __launch_bounds__(256) void edge_kernel(const int* __restrict__ ei,
                                                   const float* __restrict__ pos,
                                                   const float* __restrict__ pose,
                                                   const __hip_bfloat16* __restrict__ Zb,
                                                   float* __restrict__ out,
                                                   int E) {
    long long tid = (long long)blockIdx.x * 256 + threadIdx.x;
    if (tid >= (long long)E * P_DIM) return;
    const int e = (int)(tid >> 4);
    const int p = (int)(tid & 15);

    const int r = ei[e];
    const int c = ei[E + e];

    const float d0 = (pos[2 * c]     - pos[2 * r])     * INV2S;
    const float d1 = (pos[2 * c + 1] - pos[2 * r + 1]) * INV2S;

    const float2 ab = ((const float2*)pose)[(size_t)r * P_DIM + p];
    const float p0 = fmaf(ab.x, d0, fmaf(-ab.y, d1, 0.5f));
    const float p1 = fmaf(ab.y, d0, fmaf( ab.x, d1, 0.5f));

    const float v0 = fminf(fmaxf(p0, 0.0f), 1.0f) * 2.0f;
    const float v1 = fminf(fmaxf(p1, 0.0f), 1.0f) * 2.0f;
    const float lo0 = floorf(v0);
    const float lo1 = floorf(v1);
    const float f0 = v0 - lo0;
    const float f1 = v1 - lo1;
    const int i00 = min((int)lo0, 2);
    const int i01 = min((int)lo0 + 1, 2);
    const int i10 = min((int)lo1, 2);
    const int i11 = min((int)lo1 + 1, 2);

    const __hip_bfloat16* __restrict__ Zp = Zb + (size_t)c * PK + p * K_DIM;
    const float w00 = (1.0f - f0) * (1.0f - f1);
    const float w01 = (1.0f - f0) * f1;
    const float w10 = f0 * (1.0f - f1);
    const float w11 = f0 * f1;

    float m = w00 * __bfloat162float(Zp[i00 + 3 * i10]);
    m = fmaf(w01, __bfloat162float(Zp[i00 + 3 * i11]), m);
    m = fmaf(w10, __bfloat162float(Zp[i01 + 3 * i10]), m);
    m = fmaf(w11, __bfloat162float(Zp[i01 + 3 * i11]), m);

    atomicAdd(&out[(size_t)r * P_DIM + p], m);
}

// ---------------------------------------------------------------------------
extern "C" void kernel_launch(void* const* d_in, const int* in_sizes, int n_in,
                              void* d_out, int out_size, void* d_ws, size_t ws_size,
                              hipStream_t stream) {
    const float* x    = (const float*)d_in[0];
    const float* pos  = (const float*)d_in[1];
    const float* pose = (const float*)d_in[2];
    const float* W    = (const float*)d_in[3];
    const float* bias = (const float*)d_in[4];
    const int*   ei   = (const int*)d_in[5];

    const int N = in_sizes[0] / C_DIM;   // 50000
    const int E = in_sizes[5] / 2;       // 800000

    float* out = (float*)d_out;

    // workspace layout (all 16B-aligned: N*PK*2 = 14,400,000; NB*4 = 65,536)
    const size_t zb_bytes   = (size_t)N * PK * sizeof(__hip_bfloat16);
    const size_t hist_bytes = (size_t)NB * sizeof(int);
    const size_t sort_bytes = (size_t)E * sizeof(float4);
    __hip_bfloat16* Zb   = (__hip_bfloat16*)d_ws;
    int*            hist = (int*)((char*)d_ws + zb_bytes);
    float4*         sorted = (float4*)((char*)d_ws + zb_bytes + hist_bytes);
    const bool can_sort = ws_size >= zb_bytes + hist_bytes + sort_bytes;

    init_out_kernel<<<(N * P_DIM + 255) / 256, 256, 0, stream>>>(out, bias, N * P_DIM);
    z_gemm_kernel<<<(N + 63) / 64, 256, 0, stream>>>(x, W, Zb, N);

    if (can_sort) {
        zero_hist_kernel<<<NB / 256, 256, 0, stream>>>(hist);
        hist_kernel<<<(E + 255) / 256, 256, 0, stream>>>(ei, hist, E);
        scan_kernel<<<1, 256, 0, stream>>>(hist);
        scatter_kernel<<<(E + 255) / 256, 256, 0, stream>>>(ei, pos, hist, sorted, E);
        edge_row_kernel<<<(E + EPB - 1) / EPB, 256, 0, stream>>>(sorted, pose, Zb, out, E, N);
    } else {
        const long long total = (long long)E * P_DIM;
        edge_kernel<<<(int)((total + 255) / 256), 256, 0, stream>>>(ei, pos, pose, Zb, out, E);
    }
}

// Round 5
// 244.926 us; speedup vs baseline: 1.2525x; 1.1557x over previous
//
#include <hip/hip_runtime.h>
#include <hip/hip_bf16.h>

// Problem constants (fixed by the reference's setup_inputs)
#define C_DIM 64
#define P_DIM 16
#define K_DIM 9            // K1*K1
#define PK (P_DIM * K_DIM) // 144
#define INV2S 0.35355339059327373f  // 1/(2*sqrt(2))

// Counting-sort parameters: bucket = col >> BSHIFT
#define BSHIFT 2
#define NB 16384           // covers col < 65536 (N = 50000)

// ---------------------------------------------------------------------------
// out[n*16+p] = bias[p]
// ---------------------------------------------------------------------------
__global__ __launch_bounds__(256) void init_out_kernel(float* __restrict__ out,
                                                       const float* __restrict__ bias,
                                                       int total) {
    int i = blockIdx.x * 256 + threadIdx.x;
    if (i < total) out[i] = bias[i & (P_DIM - 1)];
}

__global__ __launch_bounds__(256) void zero_hist_kernel(int* __restrict__ hist) {
    int i = blockIdx.x * 256 + threadIdx.x;
    if (i < NB) hist[i] = 0;
}

// ---------------------------------------------------------------------------
// Zb[n, p*9+k] (bf16) = sum_c x[n,c] * W[p,k,c]   (N x 144 GEMM, K=64)
// x tile staged in LDS (row-major, padded, b128 reads); W read from global
// (147 KB, L1/L2 resident, addresses uniform across each 16-lane p-group).
// ---------------------------------------------------------------------------
__global__ __launch_bounds__(256) void z_gemm_kernel(const float* __restrict__ x,
                                                     const float* __restrict__ W,
                                                     __hip_bfloat16* __restrict__ Zb,
                                                     int N) {
    __shared__ float xs[C_DIM][C_DIM + 4];   // 64 x 68 floats = 17408 B

    const int block_row = blockIdx.x * 64;

    // stage x tile: 1024 float4s
    for (int i = threadIdx.x; i < C_DIM * (C_DIM / 4); i += 256) {
        int r = i >> 4, c4 = i & 15;
        int gr = block_row + r;
        float4 v = make_float4(0.0f, 0.0f, 0.0f, 0.0f);
        if (gr < N) v = ((const float4*)x)[(size_t)gr * (C_DIM / 4) + c4];
        *(float4*)&xs[r][c4 * 4] = v;
    }
    __syncthreads();

    const int rg = threadIdx.x & 15;   // rows rg*4 .. rg*4+3
    const int p  = threadIdx.x >> 4;   // 0..15
    const int j0 = p * K_DIM;

    float acc[4][K_DIM];
    #pragma unroll
    for (int i = 0; i < 4; ++i)
        #pragma unroll
        for (int k = 0; k < K_DIM; ++k) acc[i][k] = 0.0f;

    const float4* W4 = (const float4*)W;
    #pragma unroll 4
    for (int cs = 0; cs < 16; ++cs) {
        float4 xv[4];
        #pragma unroll
        for (int i = 0; i < 4; ++i) xv[i] = *(const float4*)&xs[rg * 4 + i][cs * 4];
        #pragma unroll
        for (int k = 0; k < K_DIM; ++k) {
            float4 wv = W4[(size_t)(j0 + k) * (C_DIM / 4) + cs];
            #pragma unroll
            for (int i = 0; i < 4; ++i) {
                acc[i][k] = fmaf(xv[i].x, wv.x, acc[i][k]);
                acc[i][k] = fmaf(xv[i].y, wv.y, acc[i][k]);
                acc[i][k] = fmaf(xv[i].z, wv.z, acc[i][k]);
                acc[i][k] = fmaf(xv[i].w, wv.w, acc[i][k]);
            }
        }
    }

    #pragma unroll
    for (int i = 0; i < 4; ++i) {
        int gr = block_row + rg * 4 + i;
        if (gr < N) {
            __hip_bfloat16* zp = Zb + (size_t)gr * PK + j0;
            #pragma unroll
            for (int k = 0; k < K_DIM; ++k) zp[k] = __float2bfloat16(acc[i][k]);
        }
    }
}

// ---------------------------------------------------------------------------
// Counting sort by col: histogram -> exclusive scan -> scatter
// ---------------------------------------------------------------------------
__global__ __launch_bounds__(256) void hist_kernel(const int* __restrict__ ei,
                                                   int* __restrict__ hist, int E) {
    int i = blockIdx.x * 256 + threadIdx.x;
    if (i < E) atomicAdd(&hist[ei[E + i] >> BSHIFT], 1);   // key = col
}

// single block, 1024 threads: in-place exclusive scan of hist[NB=16384]
__global__ __launch_bounds__(1024) void scan_kernel(int* __restrict__ hist) {
    __shared__ int sums[1024];
    const int t = threadIdx.x;
    int4* h4 = (int4*)hist;

    int4 a[4];
    #pragma unroll
    for (int q = 0; q < 4; ++q) a[q] = h4[t * 4 + q];
    int s = 0;
    #pragma unroll
    for (int q = 0; q < 4; ++q) s += a[q].x + a[q].y + a[q].z + a[q].w;

    sums[t] = s;
    __syncthreads();
    for (int off = 1; off < 1024; off <<= 1) {
        int v = (t >= off) ? sums[t - off] : 0;
        __syncthreads();
        sums[t] += v;
        __syncthreads();
    }
    int run = sums[t] - s;   // exclusive prefix of this thread's 16-chunk
    #pragma unroll
    for (int q = 0; q < 4; ++q) {
        int4 b;
        b.x = run; run += a[q].x;
        b.y = run; run += a[q].y;
        b.z = run; run += a[q].z;
        b.w = run; run += a[q].w;
        h4[t * 4 + q] = b;
    }
}

// scatter edges into col-bucket order; precompute d = (pos[c]-pos[r])*INV2S
__global__ __launch_bounds__(256) void scatter_kernel(const int* __restrict__ ei,
                                                      const float* __restrict__ pos,
                                                      int* __restrict__ offs,
                                                      float4* __restrict__ sorted,
                                                      int E) {
    int i = blockIdx.x * 256 + threadIdx.x;
    if (i >= E) return;
    const int r = ei[i];
    const int c = ei[E + i];
    const float d0 = (pos[2 * c]     - pos[2 * r])     * INV2S;
    const float d1 = (pos[2 * c + 1] - pos[2 * r + 1]) * INV2S;
    const int pidx = atomicAdd(&offs[c >> BSHIFT], 1);
    sorted[pidx] = make_float4(d0, d1, __int_as_float(r), __int_as_float(c));
}

// ---------------------------------------------------------------------------
// Edge kernel over col-sorted edges. thread-slot = (eg, p); 16 lanes share an
// edge; 4 edges per slot for memory-level parallelism (64 edges / block).
// ---------------------------------------------------------------------------
__global__ __launch_bounds__(256) void edge_sorted_kernel(const float4* __restrict__ sorted,
                                                          const float* __restrict__ pose,
                                                          const __hip_bfloat16* __restrict__ Zb,
                                                          float* __restrict__ out,
                                                          int E) {
    const int p  = threadIdx.x & 15;
    const int eg = threadIdx.x >> 4;
    const int e0 = blockIdx.x * 64 + eg;

    #pragma unroll
    for (int it = 0; it < 4; ++it) {
        const int e = e0 + it * 16;
        if (e >= E) break;

        const float4 ed = sorted[e];           // broadcast across 16 lanes
        const float d0 = ed.x, d1 = ed.y;
        const int r = __float_as_int(ed.z);
        const int c = __float_as_int(ed.w);

        const float2 ab = ((const float2*)pose)[(size_t)r * P_DIM + p];
        const float p0 = fmaf(ab.x, d0, fmaf(-ab.y, d1, 0.5f));
        const float p1 = fmaf(ab.y, d0, fmaf( ab.x, d1, 0.5f));

        const float v0 = fminf(fmaxf(p0, 0.0f), 1.0f) * 2.0f;
        const float v1 = fminf(fmaxf(p1, 0.0f), 1.0f) * 2.0f;
        const float lo0 = floorf(v0);
        const float lo1 = floorf(v1);
        const float f0 = v0 - lo0;
        const float f1 = v1 - lo1;
        const int i00 = min((int)lo0, 2);
        const int i01 = min((int)lo0 + 1, 2);
        const int i10 = min((int)lo1, 2);
        const int i11 = min((int)lo1 + 1, 2);

        const __hip_bfloat16* __restrict__ Zp = Zb + (size_t)c * PK + p * K_DIM;
        const float w00 = (1.0f - f0) * (1.0f - f1);
        const float w01 = (1.0f - f0) * f1;
        const float w10 = f0 * (1.0f - f1);
        const float w11 = f0 * f1;

        float m = w00 * __bfloat162float(Zp[i00 + 3 * i10]);
        m = fmaf(w01, __bfloat162float(Zp[i00 + 3 * i11]), m);
        m = fmaf(w10, __bfloat162float(Zp[i01 + 3 * i10]), m);
        m = fmaf(w11, __bfloat162float(Zp[i01 + 3 * i11]), m);

        atomicAdd(&out[(size_t)r * P_DIM + p], m);
    }
}

// Fallback (unsorted) edge kernel, used only if ws_size is too small for sort
__global__ __launch_bounds__(256) void edge_kernel(const int* __restrict__ ei,
                                                   const float* __restrict__ pos,
                                                   const float* __restrict__ pose,
                                                   const __hip_bfloat16* __restrict__ Zb,
                                                   float* __restrict__ out,
                                                   int E) {
    long long tid = (long long)blockIdx.x * 256 + threadIdx.x;
    if (tid >= (long long)E * P_DIM) return;
    const int e = (int)(tid >> 4);
    const int p = (int)(tid & 15);

    const int r = ei[e];
    const int c = ei[E + e];

    const float d0 = (pos[2 * c]     - pos[2 * r])     * INV2S;
    const float d1 = (pos[2 * c + 1] - pos[2 * r + 1]) * INV2S;

    const float2 ab = ((const float2*)pose)[(size_t)r * P_DIM + p];
    const float p0 = fmaf(ab.x, d0, fmaf(-ab.y, d1, 0.5f));
    const float p1 = fmaf(ab.y, d0, fmaf( ab.x, d1, 0.5f));

    const float v0 = fminf(fmaxf(p0, 0.0f), 1.0f) * 2.0f;
    const float v1 = fminf(fmaxf(p1, 0.0f), 1.0f) * 2.0f;
    const float lo0 = floorf(v0);
    const float lo1 = floorf(v1);
    const float f0 = v0 - lo0;
    const float f1 = v1 - lo1;
    const int i00 = min((int)lo0, 2);
    const int i01 = min((int)lo0 + 1, 2);
    const int i10 = min((int)lo1, 2);
    const int i11 = min((int)lo1 + 1, 2);

    const __hip_bfloat16* __restrict__ Zp = Zb + (size_t)c * PK + p * K_DIM;
    const float w00 = (1.0f - f0) * (1.0f - f1);
    const float w01 = (1.0f - f0) * f1;
    const float w10 = f0 * (1.0f - f1);
    const float w11 = f0 * f1;

    float m = w00 * __bfloat162float(Zp[i00 + 3 * i10]);
    m = fmaf(w01, __bfloat162float(Zp[i00 + 3 * i11]), m);
    m = fmaf(w10, __bfloat162float(Zp[i01 + 3 * i10]), m);
    m = fmaf(w11, __bfloat162float(Zp[i01 + 3 * i11]), m);

    atomicAdd(&out[(size_t)r * P_DIM + p], m);
}

// ---------------------------------------------------------------------------
extern "C" void kernel_launch(void* const* d_in, const int* in_sizes, int n_in,
                              void* d_out, int out_size, void* d_ws, size_t ws_size,
                              hipStream_t stream) {
    const float* x    = (const float*)d_in[0];
    const float* pos  = (const float*)d_in[1];
    const float* pose = (const float*)d_in[2];
    const float* W    = (const float*)d_in[3];
    const float* bias = (const float*)d_in[4];
    const int*   ei   = (const int*)d_in[5];

    const int N = in_sizes[0] / C_DIM;   // 50000
    const int E = in_sizes[5] / 2;       // 800000

    float* out = (float*)d_out;

    // workspace layout (16B-aligned: N*PK*2 = 14,400,000; NB*4 = 65,536)
    const size_t zb_bytes   = (size_t)N * PK * sizeof(__hip_bfloat16);
    const size_t hist_bytes = (size_t)NB * sizeof(int);
    const size_t sort_bytes = (size_t)E * sizeof(float4);
    __hip_bfloat16* Zb     = (__hip_bfloat16*)d_ws;
    int*            hist   = (int*)((char*)d_ws + zb_bytes);
    float4*         sorted = (float4*)((char*)d_ws + zb_bytes + hist_bytes);
    const bool can_sort = ws_size >= zb_bytes + hist_bytes + sort_bytes;

    init_out_kernel<<<(N * P_DIM + 255) / 256, 256, 0, stream>>>(out, bias, N * P_DIM);
    z_gemm_kernel<<<(N + 63) / 64, 256, 0, stream>>>(x, W, Zb, N);

    if (can_sort) {
        zero_hist_kernel<<<NB / 256, 256, 0, stream>>>(hist);
        hist_kernel<<<(E + 255) / 256, 256, 0, stream>>>(ei, hist, E);
        scan_kernel<<<1, 1024, 0, stream>>>(hist);
        scatter_kernel<<<(E + 255) / 256, 256, 0, stream>>>(ei, pos, hist, sorted, E);
        edge_sorted_kernel<<<(E + 63) / 64, 256, 0, stream>>>(sorted, pose, Zb, out, E);
    } else {
        const long long total = (long long)E * P_DIM;
        edge_kernel<<<(int)((total + 255) / 256), 256, 0, stream>>>(ei, pos, pose, Zb, out, E);
    }
}

// Round 6
// 158.561 us; speedup vs baseline: 1.9346x; 1.5447x over previous
//
#include <hip/hip_runtime.h>
#include <hip/hip_bf16.h>

// Problem constants (fixed by the reference's setup_inputs)
#define C_DIM 64
#define P_DIM 16
#define K_DIM 9            // K1*K1
#define PK (P_DIM * K_DIM) // 144
#define INV2S 0.35355339059327373f  // 1/(2*sqrt(2))

// ---------------------------------------------------------------------------
// out[n*16+p] = bias[p]   (d_out is poisoned each call)
// ---------------------------------------------------------------------------
__global__ __launch_bounds__(256) void init_out_kernel(float* __restrict__ out,
                                                       const float* __restrict__ bias,
                                                       int total) {
    int i = blockIdx.x * 256 + threadIdx.x;
    if (i < total) out[i] = bias[i & (P_DIM - 1)];
}

// ---------------------------------------------------------------------------
// Zb[n, p*9+k] (bf16) = sum_c x[n,c] * W[p,k,c]   (N x 144 GEMM, K=64)
// x tile in LDS (row-major, +4 pad). Thread (rg,p) computes rows rg+16*i
// (stride-1 across lanes -> LDS bank stride 4 -> only 2-way aliasing, free).
// W read from global (147 KB, L1/L2 resident, wave-uniform per p-group).
// ---------------------------------------------------------------------------
__global__ __launch_bounds__(256) void z_gemm_kernel(const float* __restrict__ x,
                                                     const float* __restrict__ W,
                                                     __hip_bfloat16* __restrict__ Zb,
                                                     int N) {
    __shared__ float xs[C_DIM][C_DIM + 4];   // 64 x 68 floats = 17408 B

    const int block_row = blockIdx.x * 64;

    // stage x tile: 1024 float4s
    for (int i = threadIdx.x; i < C_DIM * (C_DIM / 4); i += 256) {
        int r = i >> 4, c4 = i & 15;
        int gr = block_row + r;
        float4 v = make_float4(0.0f, 0.0f, 0.0f, 0.0f);
        if (gr < N) v = ((const float4*)x)[(size_t)gr * (C_DIM / 4) + c4];
        *(float4*)&xs[r][c4 * 4] = v;
    }
    __syncthreads();

    const int rg = threadIdx.x & 15;   // rows rg, rg+16, rg+32, rg+48
    const int p  = threadIdx.x >> 4;   // 0..15
    const int j0 = p * K_DIM;

    float acc[4][K_DIM];
    #pragma unroll
    for (int i = 0; i < 4; ++i)
        #pragma unroll
        for (int k = 0; k < K_DIM; ++k) acc[i][k] = 0.0f;

    const float4* W4 = (const float4*)W;
    #pragma unroll 4
    for (int cs = 0; cs < 16; ++cs) {
        float4 xv[4];
        #pragma unroll
        for (int i = 0; i < 4; ++i) xv[i] = *(const float4*)&xs[rg + 16 * i][cs * 4];
        #pragma unroll
        for (int k = 0; k < K_DIM; ++k) {
            float4 wv = W4[(size_t)(j0 + k) * (C_DIM / 4) + cs];
            #pragma unroll
            for (int i = 0; i < 4; ++i) {
                acc[i][k] = fmaf(xv[i].x, wv.x, acc[i][k]);
                acc[i][k] = fmaf(xv[i].y, wv.y, acc[i][k]);
                acc[i][k] = fmaf(xv[i].z, wv.z, acc[i][k]);
                acc[i][k] = fmaf(xv[i].w, wv.w, acc[i][k]);
            }
        }
    }

    #pragma unroll
    for (int i = 0; i < 4; ++i) {
        int gr = block_row + rg + 16 * i;
        if (gr < N) {
            __hip_bfloat16* zp = Zb + (size_t)gr * PK + j0;
            #pragma unroll
            for (int k = 0; k < K_DIM; ++k) zp[k] = __float2bfloat16(acc[i][k]);
        }
    }
}

// ---------------------------------------------------------------------------
// Edge kernel (unsorted). thread-slot = (eg, p); 16 lanes share an edge;
// 4 edges per slot (64 edges / block), fully unrolled + predicated for MLP.
// ---------------------------------------------------------------------------
__global__ __launch_bounds__(256) void edge_kernel(const int* __restrict__ ei,
                                                   const float* __restrict__ pos,
                                                   const float* __restrict__ pose,
                                                   const __hip_bfloat16* __restrict__ Zb,
                                                   float* __restrict__ out,
                                                   int E) {
    const int p  = threadIdx.x & 15;
    const int eg = threadIdx.x >> 4;
    const int e0 = blockIdx.x * 64 + eg;

    int  r[4], c[4];
    bool valid[4];
    #pragma unroll
    for (int it = 0; it < 4; ++it) {
        int e = e0 + it * 16;
        valid[it] = (e < E);
        int ec = valid[it] ? e : 0;
        r[it] = ei[ec];
        c[it] = ei[E + ec];
    }

    float d0[4], d1[4];
    #pragma unroll
    for (int it = 0; it < 4; ++it) {
        d0[it] = (pos[2 * c[it]]     - pos[2 * r[it]])     * INV2S;
        d1[it] = (pos[2 * c[it] + 1] - pos[2 * r[it] + 1]) * INV2S;
    }

    float2 ab[4];
    #pragma unroll
    for (int it = 0; it < 4; ++it)
        ab[it] = ((const float2*)pose)[(size_t)r[it] * P_DIM + p];

    #pragma unroll
    for (int it = 0; it < 4; ++it) {
        const float p0 = fmaf(ab[it].x, d0[it], fmaf(-ab[it].y, d1[it], 0.5f));
        const float p1 = fmaf(ab[it].y, d0[it], fmaf( ab[it].x, d1[it], 0.5f));

        const float v0 = fminf(fmaxf(p0, 0.0f), 1.0f) * 2.0f;
        const float v1 = fminf(fmaxf(p1, 0.0f), 1.0f) * 2.0f;
        const float lo0 = floorf(v0);
        const float lo1 = floorf(v1);
        const float f0 = v0 - lo0;
        const float f1 = v1 - lo1;
        const int i00 = min((int)lo0, 2);
        const int i01 = min((int)lo0 + 1, 2);
        const int i10 = min((int)lo1, 2);
        const int i11 = min((int)lo1 + 1, 2);

        const __hip_bfloat16* __restrict__ Zp = Zb + (size_t)c[it] * PK + p * K_DIM;
        const float w00 = (1.0f - f0) * (1.0f - f1);
        const float w01 = (1.0f - f0) * f1;
        const float w10 = f0 * (1.0f - f1);
        const float w11 = f0 * f1;

        float m = w00 * __bfloat162float(Zp[i00 + 3 * i10]);
        m = fmaf(w01, __bfloat162float(Zp[i00 + 3 * i11]), m);
        m = fmaf(w10, __bfloat162float(Zp[i01 + 3 * i10]), m);
        m = fmaf(w11, __bfloat162float(Zp[i01 + 3 * i11]), m);

        if (valid[it]) atomicAdd(&out[(size_t)r[it] * P_DIM + p], m);
    }
}

// ---------------------------------------------------------------------------
extern "C" void kernel_launch(void* const* d_in, const int* in_sizes, int n_in,
                              void* d_out, int out_size, void* d_ws, size_t ws_size,
                              hipStream_t stream) {
    const float* x    = (const float*)d_in[0];
    const float* pos  = (const float*)d_in[1];
    const float* pose = (const float*)d_in[2];
    const float* W    = (const float*)d_in[3];
    const float* bias = (const float*)d_in[4];
    const int*   ei   = (const int*)d_in[5];

    const int N = in_sizes[0] / C_DIM;   // 50000
    const int E = in_sizes[5] / 2;       // 800000

    float* out = (float*)d_out;
    __hip_bfloat16* Zb = (__hip_bfloat16*)d_ws;   // N * 144 bf16 = 14.4 MB

    init_out_kernel<<<(N * P_DIM + 255) / 256, 256, 0, stream>>>(out, bias, N * P_DIM);
    z_gemm_kernel<<<(N + 63) / 64, 256, 0, stream>>>(x, W, Zb, N);
    edge_kernel<<<(E + 63) / 64, 256, 0, stream>>>(ei, pos, pose, Zb, out, E);
}

// Round 9
// 156.264 us; speedup vs baseline: 1.9631x; 1.0147x over previous
//
#include <hip/hip_runtime.h>
#include <hip/hip_bf16.h>

// Problem constants (fixed by the reference's setup_inputs)
#define C_DIM 64
#define P_DIM 16
#define K_DIM 9            // K1*K1
#define PK (P_DIM * K_DIM) // 144
#define INV2S 0.35355339059327373f  // 1/(2*sqrt(2))

// LDS staging row stride for the z epilogue, in halfwords (bf16).
// 152 hw = 304 B: 16B-aligned rows (304/16=19), lane bank-stride 12 -> <=2-way.
#define ZS_STRIDE 152
// shared buffer: max(64*68*4, 64*152*2) = max(17408, 19456) = 19456 B
#define SH_FLOATS 4864

// ---------------------------------------------------------------------------
// Kernel 1: fused  (a) out[n*16+p] = bias[p] for this block's 64 rows
//                  (b) Zb[n, p*9+k] (bf16) = sum_c x[n,c] * W[p,k,c]
// x tile in LDS; W from global (147 KB, L1/L2 resident). Epilogue stages the
// 64x144 bf16 tile in LDS and writes coalesced float4s.
// ---------------------------------------------------------------------------
__global__ __launch_bounds__(256) void z_gemm_kernel(const float* __restrict__ x,
                                                     const float* __restrict__ W,
                                                     const float* __restrict__ bias,
                                                     float* __restrict__ out,
                                                     __hip_bfloat16* __restrict__ Zb,
                                                     int N) {
    __shared__ float sh_raw[SH_FLOATS];
    float (*xs)[C_DIM + 4] = (float(*)[C_DIM + 4])sh_raw;     // [64][68]
    __hip_bfloat16* zs = (__hip_bfloat16*)sh_raw;             // [64 * 152]

    const int block_row = blockIdx.x * 64;
    const int tid = threadIdx.x;

    // (a) bias-init this block's slice of out: 64 rows x 16 = 256 float4s
    {
        const float4 b4 = ((const float4*)bias)[tid & 3];
        const int o4 = block_row * 4 + tid;          // float4 index into out
        if (o4 < N * 4) ((float4*)out)[o4] = b4;
    }

    // stage x tile: 1024 float4s
    for (int i = tid; i < C_DIM * (C_DIM / 4); i += 256) {
        int r = i >> 4, c4 = i & 15;
        int gr = block_row + r;
        float4 v = make_float4(0.0f, 0.0f, 0.0f, 0.0f);
        if (gr < N) v = ((const float4*)x)[(size_t)gr * (C_DIM / 4) + c4];
        *(float4*)&xs[r][c4 * 4] = v;
    }
    __syncthreads();

    const int rg = tid & 15;   // rows rg, rg+16, rg+32, rg+48
    const int p  = tid >> 4;   // 0..15
    const int j0 = p * K_DIM;

    float acc[4][K_DIM];
    #pragma unroll
    for (int i = 0; i < 4; ++i)
        #pragma unroll
        for (int k = 0; k < K_DIM; ++k) acc[i][k] = 0.0f;

    const float4* W4 = (const float4*)W;
    #pragma unroll 4
    for (int cs = 0; cs < 16; ++cs) {
        float4 xv[4];
        #pragma unroll
        for (int i = 0; i < 4; ++i) xv[i] = *(const float4*)&xs[rg + 16 * i][cs * 4];
        #pragma unroll
        for (int k = 0; k < K_DIM; ++k) {
            float4 wv = W4[(size_t)(j0 + k) * (C_DIM / 4) + cs];
            #pragma unroll
            for (int i = 0; i < 4; ++i) {
                acc[i][k] = fmaf(xv[i].x, wv.x, acc[i][k]);
                acc[i][k] = fmaf(xv[i].y, wv.y, acc[i][k]);
                acc[i][k] = fmaf(xv[i].z, wv.z, acc[i][k]);
                acc[i][k] = fmaf(xv[i].w, wv.w, acc[i][k]);
            }
        }
    }
    __syncthreads();   // done reading xs; reuse LDS as zs

    // stage bf16 results in LDS
    #pragma unroll
    for (int i = 0; i < 4; ++i) {
        __hip_bfloat16* zrow = &zs[(rg + 16 * i) * ZS_STRIDE + j0];
        #pragma unroll
        for (int k = 0; k < K_DIM; ++k)
            zrow[k] = __float2bfloat16(acc[i][k]);
    }
    __syncthreads();

    // coalesced write-out: 64 rows x 18 float4 = 1152 float4s
    const int nrow = min(64, N - block_row);
    float4* Zb4 = (float4*)Zb;
    for (int i = tid; i < nrow * 18; i += 256) {
        int row = i / 18, q = i - row * 18;
        float4 v = *(const float4*)&zs[row * ZS_STRIDE + q * 8];
        Zb4[(size_t)(block_row + row) * 18 + q] = v;
    }
}

// ---------------------------------------------------------------------------
// Kernel 2: edge messages + scatter-add (unsorted).
// thread-slot = (eg, p); 16 lanes share an edge; 8 edges per slot
// (128 edges / block), fully unrolled + predicated for memory-level par.
// ---------------------------------------------------------------------------
#define EILP 8
__global__ __launch_bounds__(256) void edge_kernel(const int* __restrict__ ei,
                                                   const float* __restrict__ pos,
                                                   const float* __restrict__ pose,
                                                   const __hip_bfloat16* __restrict__ Zb,
                                                   float* __restrict__ out,
                                                   int E) {
    const int p  = threadIdx.x & 15;
    const int eg = threadIdx.x >> 4;
    const int e0 = blockIdx.x * (16 * EILP) + eg;

    int  r[EILP], c[EILP];
    bool valid[EILP];
    #pragma unroll
    for (int it = 0; it < EILP; ++it) {
        int e = e0 + it * 16;
        valid[it] = (e < E);
        int ec = valid[it] ? e : 0;
        r[it] = ei[ec];
        c[it] = ei[E + ec];
    }

    float d0[EILP], d1[EILP];
    #pragma unroll
    for (int it = 0; it < EILP; ++it) {
        const float2 pc = ((const float2*)pos)[c[it]];
        const float2 pr = ((const float2*)pos)[r[it]];
        d0[it] = (pc.x - pr.x) * INV2S;
        d1[it] = (pc.y - pr.y) * INV2S;
    }

    float2 ab[EILP];
    #pragma unroll
    for (int it = 0; it < EILP; ++it)
        ab[it] = ((const float2*)pose)[(size_t)r[it] * P_DIM + p];

    #pragma unroll
    for (int it = 0; it < EILP; ++it) {
        const float p0 = fmaf(ab[it].x, d0[it], fmaf(-ab[it].y, d1[it], 0.5f));
        const float p1 = fmaf(ab[it].y, d0[it], fmaf( ab[it].x, d1[it], 0.5f));

        const float v0 = fminf(fmaxf(p0, 0.0f), 1.0f) * 2.0f;
        const float v1 = fminf(fmaxf(p1, 0.0f), 1.0f) * 2.0f;
        const float lo0 = floorf(v0);
        const float lo1 = floorf(v1);
        const float f0 = v0 - lo0;
        const float f1 = v1 - lo1;
        const int i00 = min((int)lo0, 2);
        const int i01 = min((int)lo0 + 1, 2);
        const int i10 = min((int)lo1, 2);
        const int i11 = min((int)lo1 + 1, 2);

        const __hip_bfloat16* __restrict__ Zp = Zb + (size_t)c[it] * PK + p * K_DIM;
        const float w00 = (1.0f - f0) * (1.0f - f1);
        const float w01 = (1.0f - f0) * f1;
        const float w10 = f0 * (1.0f - f1);
        const float w11 = f0 * f1;

        float m = w00 * __bfloat162float(Zp[i00 + 3 * i10]);
        m = fmaf(w01, __bfloat162float(Zp[i00 + 3 * i11]), m);
        m = fmaf(w10, __bfloat162float(Zp[i01 + 3 * i10]), m);
        m = fmaf(w11, __bfloat162float(Zp[i01 + 3 * i11]), m);

        if (valid[it]) atomicAdd(&out[(size_t)r[it] * P_DIM + p], m);
    }
}

// ---------------------------------------------------------------------------
extern "C" void kernel_launch(void* const* d_in, const int* in_sizes, int n_in,
                              void* d_out, int out_size, void* d_ws, size_t ws_size,
                              hipStream_t stream) {
    const float* x    = (const float*)d_in[0];
    const float* pos  = (const float*)d_in[1];
    const float* pose = (const float*)d_in[2];
    const float* W    = (const float*)d_in[3];
    const float* bias = (const float*)d_in[4];
    const int*   ei   = (const int*)d_in[5];

    const int N = in_sizes[0] / C_DIM;   // 50000
    const int E = in_sizes[5] / 2;       // 800000

    float* out = (float*)d_out;
    __hip_bfloat16* Zb = (__hip_bfloat16*)d_ws;   // N * 144 bf16 = 14.4 MB

    z_gemm_kernel<<<(N + 63) / 64, 256, 0, stream>>>(x, W, bias, out, Zb, N);
    edge_kernel<<<(E + 16 * EILP - 1) / (16 * EILP), 256, 0, stream>>>(ei, pos, pose, Zb, out, E);
}